// Round 1
// baseline (703.287 us; speedup 1.0000x reference)
//
#include <hip/hip_runtime.h>

// ---------- helpers ----------
typedef __attribute__((ext_vector_type(8))) short short8;
typedef __attribute__((ext_vector_type(4))) float f32x4;

__device__ __forceinline__ unsigned short f2bf(float f) {
    union { float f; unsigned u; } v; v.f = f;
    unsigned r = v.u + 0x7FFFu + ((v.u >> 16) & 1u);   // RNE
    return (unsigned short)(r >> 16);
}
__device__ __forceinline__ float bf2f(unsigned short h) {
    union { unsigned u; float f; } v; v.u = ((unsigned)h) << 16;
    return v.f;
}

// ---------- cast f32 -> bf16 (4 elems / thread) ----------
__global__ __launch_bounds__(256) void cast_f32_bf16(
    const float* __restrict__ src, unsigned short* __restrict__ dst, int n)
{
    int t = (blockIdx.x * 256 + threadIdx.x) * 4;
    if (t >= n) return;
    float4 v = *(const float4*)(src + t);
    unsigned long long p =
        (unsigned long long)f2bf(v.x)
      | ((unsigned long long)f2bf(v.y) << 16)
      | ((unsigned long long)f2bf(v.z) << 32)
      | ((unsigned long long)f2bf(v.w) << 48);
    *(unsigned long long*)(dst + t) = p;
}

// ---------- MFMA GEMM: C[M,N] = act(A[M,K] * B[N,K]^T + bias) ----------
// A row-major bf16, B row-major [N,K] bf16 (weights as given), C bf16.
#define TM 128
#define TN 128
#define BK 64
#define PAD 8

template<bool TANH>
__global__ __launch_bounds__(256) void gemm_bt(
    const unsigned short* __restrict__ A, const unsigned short* __restrict__ B,
    const float* __restrict__ bias, unsigned short* __restrict__ C,
    int M, int N, int K)
{
    __shared__ __align__(16) short As[TM][BK + PAD];
    __shared__ __align__(16) short Bs[TN][BK + PAD];

    const int tid  = threadIdx.x;
    const int wave = tid >> 6;
    const int lane = tid & 63;
    const int m0 = blockIdx.x * TM;
    const int n0 = blockIdx.y * TN;
    const int wm = (wave >> 1) * 64;
    const int wn = (wave & 1) * 64;
    const int lm = lane & 15;
    const int quad = lane >> 4;

    f32x4 acc[4][4] = {};

    for (int k0 = 0; k0 < K; k0 += BK) {
        // stage 128x64 A-tile and B-tile: 1024 chunks of 8 bf16 each
        #pragma unroll
        for (int i = 0; i < 4; ++i) {
            int idx = i * 256 + tid;
            int row = idx >> 3;          // 0..127
            int c   = idx & 7;           // 0..7 (8 bf16 per chunk)
            int gr = m0 + row; if (gr >= M) gr = M - 1;   // clamp tail
            uint4 va = *(const uint4*)(A + (size_t)gr * K + k0 + c * 8);
            *(uint4*)&As[row][c * 8] = va;
            int gn = n0 + row;           // N is a multiple of 128
            uint4 vb = *(const uint4*)(B + (size_t)gn * K + k0 + c * 8);
            *(uint4*)&Bs[row][c * 8] = vb;
        }
        __syncthreads();

        #pragma unroll
        for (int ks = 0; ks < BK; ks += 32) {
            short8 af[4], bf_[4];
            #pragma unroll
            for (int i = 0; i < 4; ++i) {
                af[i]  = *(const short8*)&As[wm + i * 16 + lm][ks + quad * 8];
                bf_[i] = *(const short8*)&Bs[wn + i * 16 + lm][ks + quad * 8];
            }
            #pragma unroll
            for (int im = 0; im < 4; ++im)
                #pragma unroll
                for (int in = 0; in < 4; ++in)
                    acc[im][in] = __builtin_amdgcn_mfma_f32_16x16x32_bf16(
                        af[im], bf_[in], acc[im][in], 0, 0, 0);
        }
        __syncthreads();
    }

    // epilogue: D row = quad*4 + reg, col = lane&15
    #pragma unroll
    for (int im = 0; im < 4; ++im) {
        int gm_base = m0 + wm + im * 16 + quad * 4;
        #pragma unroll
        for (int in = 0; in < 4; ++in) {
            int gn = n0 + wn + in * 16 + lm;
            float bv = bias[gn];
            #pragma unroll
            for (int r = 0; r < 4; ++r) {
                int gm = gm_base + r;
                if (gm < M) {
                    float v = acc[im][in][r] + bv;
                    if (TANH) v = tanhf(v);
                    C[(size_t)gm * N + gn] = f2bf(v);
                }
            }
        }
    }
}

// ---------- edge scatter: 128 threads per edge ----------
__global__ __launch_bounds__(256) void edge_scatter(
    const unsigned short* __restrict__ h, const float* __restrict__ alpha,
    const int* __restrict__ ei, float* __restrict__ out,
    float* __restrict__ cnt, int E)
{
    int t = blockIdx.x * 256 + threadIdx.x;
    int e = t >> 7;
    int f = t & 127;
    if (e >= E) return;
    int src = ei[e];
    int dst = ei[E + e];
    float a = alpha[e];
    float gate = 2.0f * fmaxf(a - 0.5f, 0.0f);
    if (f == 0) unsafeAtomicAdd(cnt + dst, 1.0f);
    if (gate > 0.0f) {
        float v = bf2f(h[(size_t)src * 128 + f]) * gate;
        unsafeAtomicAdd(out + (size_t)dst * 128 + f, v);
    }
}

// ---------- finalize: scatter-mean ----------
__global__ __launch_bounds__(256) void finalize_mean(
    float* __restrict__ out, const float* __restrict__ cnt, int total)
{
    int t = blockIdx.x * 256 + threadIdx.x;
    if (t >= total) return;
    int n = t >> 7;
    out[t] = out[t] / fmaxf(cnt[n], 1.0f);
}

// ---------- launch ----------
extern "C" void kernel_launch(void* const* d_in, const int* in_sizes, int n_in,
                              void* d_out, int out_size, void* d_ws, size_t ws_size,
                              hipStream_t stream) {
    const float* x     = (const float*)d_in[0];
    const float* alpha = (const float*)d_in[1];
    const int*   ei    = (const int*)d_in[2];
    // d_in[3] = norm, unused by the reference math
    const float* W1 = (const float*)d_in[4];
    const float* b1 = (const float*)d_in[5];
    const float* W2 = (const float*)d_in[6];
    const float* b2 = (const float*)d_in[7];
    const float* W3 = (const float*)d_in[8];
    const float* b3 = (const float*)d_in[9];
    float* out = (float*)d_out;

    const int N = in_sizes[0] / 256;   // 100000
    const int E = in_sizes[1];         // 640000
    const int IN = 256, H1 = 512, H2 = 256, D = 128;

    // workspace layout (bytes, 256-aligned)
    char* ws = (char*)d_ws;
    size_t off = 0;
    auto take = [&](size_t bytes) { char* p = ws + off; off = (off + bytes + 255) & ~(size_t)255; return p; };
    unsigned short* xbf  = (unsigned short*)take((size_t)N * IN * 2);   // also reused as h2bf
    unsigned short* h1bf = (unsigned short*)take((size_t)N * H1 * 2);
    unsigned short* hbf  = (unsigned short*)take((size_t)N * D  * 2);
    unsigned short* w1bf = (unsigned short*)take((size_t)H1 * IN * 2);
    unsigned short* w2bf = (unsigned short*)take((size_t)H2 * H1 * 2);
    unsigned short* w3bf = (unsigned short*)take((size_t)D  * H2 * 2);
    float* cnt = (float*)take((size_t)N * 4);
    unsigned short* h2bf = xbf;  // GEMM2 reads h1bf only; x dead after GEMM1

    // zero accumulators
    hipMemsetAsync(out, 0, (size_t)N * D * 4, stream);
    hipMemsetAsync(cnt, 0, (size_t)N * 4, stream);

    // casts
    cast_f32_bf16<<<(N * IN / 4 + 255) / 256, 256, 0, stream>>>(x,  xbf,  N * IN);
    cast_f32_bf16<<<(H1 * IN / 4 + 255) / 256, 256, 0, stream>>>(W1, w1bf, H1 * IN);
    cast_f32_bf16<<<(H2 * H1 / 4 + 255) / 256, 256, 0, stream>>>(W2, w2bf, H2 * H1);
    cast_f32_bf16<<<(D * H2 / 4 + 255) / 256, 256, 0, stream>>>(W3, w3bf, D * H2);

    const int mblk = (N + TM - 1) / TM;  // 782
    dim3 blk(256);
    // h1 = tanh(x @ W1^T)
    gemm_bt<true ><<<dim3(mblk, H1 / TN), blk, 0, stream>>>(xbf,  w1bf, b1, h1bf, N, H1, IN);
    // h2 = tanh(h1 @ W2^T)
    gemm_bt<true ><<<dim3(mblk, H2 / TN), blk, 0, stream>>>(h1bf, w2bf, b2, h2bf, N, H2, H1);
    // h = h2 @ W3^T
    gemm_bt<false><<<dim3(mblk, D / TN),  blk, 0, stream>>>(h2bf, w3bf, b3, hbf,  N, D,  H2);

    // edge gather + gate + scatter-add (+ per-edge count)
    long long et = (long long)E * 128;
    edge_scatter<<<(unsigned)((et + 255) / 256), blk, 0, stream>>>(hbf, alpha, ei, out, cnt, E);

    // mean
    finalize_mean<<<(N * D + 255) / 256, blk, 0, stream>>>(out, cnt, N * D);
}

// Round 2
// 523.149 us; speedup vs baseline: 1.3443x; 1.3443x over previous
//
#include <hip/hip_runtime.h>

// ---------- helpers ----------
typedef __attribute__((ext_vector_type(8))) short short8;
typedef __attribute__((ext_vector_type(4))) float f32x4;

__device__ __forceinline__ unsigned short f2bf(float f) {
    union { float f; unsigned u; } v; v.f = f;
    unsigned r = v.u + 0x7FFFu + ((v.u >> 16) & 1u);   // RNE
    return (unsigned short)(r >> 16);
}
__device__ __forceinline__ float bf2f(unsigned short h) {
    union { unsigned u; float f; } v; v.u = ((unsigned)h) << 16;
    return v.f;
}

// ---------- cast f32 -> bf16 (4 elems / thread) ----------
__global__ __launch_bounds__(256) void cast_f32_bf16(
    const float* __restrict__ src, unsigned short* __restrict__ dst, int n)
{
    int t = (blockIdx.x * 256 + threadIdx.x) * 4;
    if (t >= n) return;
    float4 v = *(const float4*)(src + t);
    unsigned long long p =
        (unsigned long long)f2bf(v.x)
      | ((unsigned long long)f2bf(v.y) << 16)
      | ((unsigned long long)f2bf(v.z) << 32)
      | ((unsigned long long)f2bf(v.w) << 48);
    *(unsigned long long*)(dst + t) = p;
}

// ---------- MFMA GEMM: C[M,N] = act(A[M,K] * B[N,K]^T + bias) ----------
#define TM 128
#define TN 128
#define BK 64
#define PAD 8

template<bool TANH>
__global__ __launch_bounds__(256) void gemm_bt(
    const unsigned short* __restrict__ A, const unsigned short* __restrict__ B,
    const float* __restrict__ bias, unsigned short* __restrict__ C,
    int M, int N, int K)
{
    __shared__ __align__(16) short As[TM][BK + PAD];
    __shared__ __align__(16) short Bs[TN][BK + PAD];

    const int tid  = threadIdx.x;
    const int wave = tid >> 6;
    const int lane = tid & 63;
    const int m0 = blockIdx.x * TM;
    const int n0 = blockIdx.y * TN;
    const int wm = (wave >> 1) * 64;
    const int wn = (wave & 1) * 64;
    const int lm = lane & 15;
    const int quad = lane >> 4;

    f32x4 acc[4][4] = {};

    for (int k0 = 0; k0 < K; k0 += BK) {
        #pragma unroll
        for (int i = 0; i < 4; ++i) {
            int idx = i * 256 + tid;
            int row = idx >> 3;
            int c   = idx & 7;
            int gr = m0 + row; if (gr >= M) gr = M - 1;
            uint4 va = *(const uint4*)(A + (size_t)gr * K + k0 + c * 8);
            *(uint4*)&As[row][c * 8] = va;
            int gn = n0 + row;
            uint4 vb = *(const uint4*)(B + (size_t)gn * K + k0 + c * 8);
            *(uint4*)&Bs[row][c * 8] = vb;
        }
        __syncthreads();

        #pragma unroll
        for (int ks = 0; ks < BK; ks += 32) {
            short8 af[4], bf_[4];
            #pragma unroll
            for (int i = 0; i < 4; ++i) {
                af[i]  = *(const short8*)&As[wm + i * 16 + lm][ks + quad * 8];
                bf_[i] = *(const short8*)&Bs[wn + i * 16 + lm][ks + quad * 8];
            }
            #pragma unroll
            for (int im = 0; im < 4; ++im)
                #pragma unroll
                for (int in = 0; in < 4; ++in)
                    acc[im][in] = __builtin_amdgcn_mfma_f32_16x16x32_bf16(
                        af[im], bf_[in], acc[im][in], 0, 0, 0);
        }
        __syncthreads();
    }

    #pragma unroll
    for (int im = 0; im < 4; ++im) {
        int gm_base = m0 + wm + im * 16 + quad * 4;
        #pragma unroll
        for (int in = 0; in < 4; ++in) {
            int gn = n0 + wn + in * 16 + lm;
            float bv = bias[gn];
            #pragma unroll
            for (int r = 0; r < 4; ++r) {
                int gm = gm_base + r;
                if (gm < M) {
                    float v = acc[im][in][r] + bv;
                    if (TANH) v = tanhf(v);
                    C[(size_t)gm * N + gn] = f2bf(v);
                }
            }
        }
    }
}

// ---------- edge histogram: packed (degAll<<32 | degGated) ----------
__global__ __launch_bounds__(256) void edge_hist(
    const int* __restrict__ ei, const float* __restrict__ alpha,
    unsigned long long* __restrict__ deg, int E)
{
    int e = blockIdx.x * 256 + threadIdx.x;
    if (e >= E) return;
    int dst = ei[E + e];
    float gate = 2.0f * fmaxf(alpha[e] - 0.5f, 0.0f);
    atomicAdd(&deg[dst], 0x100000000ULL | (gate > 0.0f ? 1ULL : 0ULL));
}

// ---------- scan step 1: per-block (1024 elems) exclusive scan ----------
__global__ __launch_bounds__(256) void scan1(
    const unsigned long long* __restrict__ deg, int* __restrict__ rowptr,
    int* __restrict__ partials, int N)
{
    __shared__ int sums[256];
    int base = blockIdx.x * 1024 + threadIdx.x * 4;
    int v[4];
    #pragma unroll
    for (int i = 0; i < 4; ++i) {
        int idx = base + i;
        v[i] = (idx < N) ? (int)(deg[idx] & 0xffffffffULL) : 0;
    }
    int s = v[0] + v[1] + v[2] + v[3];
    sums[threadIdx.x] = s;
    __syncthreads();
    for (int off = 1; off < 256; off <<= 1) {
        int t = (threadIdx.x >= off) ? sums[threadIdx.x - off] : 0;
        __syncthreads();
        sums[threadIdx.x] += t;
        __syncthreads();
    }
    int excl = sums[threadIdx.x] - s;
    if (threadIdx.x == 255) partials[blockIdx.x] = sums[255];
    int run = excl;
    #pragma unroll
    for (int i = 0; i < 4; ++i) {
        int idx = base + i;
        if (idx < N) rowptr[idx] = run;
        run += v[i];
    }
}

// ---------- scan step 2: scan the block partials (single block) ----------
__global__ __launch_bounds__(256) void scan2(int* __restrict__ partials, int nb)
{
    __shared__ int s[256];
    int v = (threadIdx.x < nb) ? partials[threadIdx.x] : 0;
    s[threadIdx.x] = v;
    __syncthreads();
    for (int off = 1; off < 256; off <<= 1) {
        int t = (threadIdx.x >= off) ? s[threadIdx.x - off] : 0;
        __syncthreads();
        s[threadIdx.x] += t;
        __syncthreads();
    }
    partials[threadIdx.x] = s[threadIdx.x] - v;   // exclusive
}

// ---------- scan step 3: add block offsets; init cursor ----------
__global__ __launch_bounds__(256) void scan3(
    int* __restrict__ rowptr, int* __restrict__ cursor,
    const int* __restrict__ partials, int N)
{
    int i = blockIdx.x * 256 + threadIdx.x;
    if (i >= N) return;
    int r = rowptr[i] + partials[i >> 10];
    rowptr[i] = r;
    cursor[i] = r;
}

// ---------- fill CSR with gated edges only ----------
__global__ __launch_bounds__(256) void edge_fill(
    const int* __restrict__ ei, const float* __restrict__ alpha,
    int* __restrict__ cursor, int2* __restrict__ recs, int E)
{
    int e = blockIdx.x * 256 + threadIdx.x;
    if (e >= E) return;
    float gate = 2.0f * fmaxf(alpha[e] - 0.5f, 0.0f);
    if (gate > 0.0f) {
        int dst = ei[E + e];
        int src = ei[e];
        int pos = atomicAdd(&cursor[dst], 1);
        recs[pos] = make_int2(src, __float_as_int(gate));
    }
}

// ---------- per-node gather + mean: one wave per node ----------
__global__ __launch_bounds__(256) void node_gather(
    const unsigned short* __restrict__ h, const unsigned long long* __restrict__ deg,
    const int* __restrict__ rowptr, const int2* __restrict__ recs,
    float* __restrict__ out, int N)
{
    int wave = threadIdx.x >> 6;
    int lane = threadIdx.x & 63;
    int node = blockIdx.x * 4 + wave;
    if (node >= N) return;
    unsigned long long d = deg[node];
    int dAll  = __builtin_amdgcn_readfirstlane((int)(d >> 32));
    int dG    = __builtin_amdgcn_readfirstlane((int)(d & 0xffffffffULL));
    int start = __builtin_amdgcn_readfirstlane(rowptr[node]);
    float ax = 0.0f, ay = 0.0f;
    for (int j = 0; j < dG; ++j) {
        int2 rec = recs[start + j];                 // wave-uniform load
        float gate = __int_as_float(rec.y);
        unsigned u = *(const unsigned*)(h + ((size_t)rec.x << 7) + lane * 2);
        ax += bf2f((unsigned short)(u & 0xffffu)) * gate;
        ay += bf2f((unsigned short)(u >> 16)) * gate;
    }
    float inv = 1.0f / fmaxf((float)dAll, 1.0f);
    *(float2*)(out + ((size_t)node << 7) + lane * 2) = make_float2(ax * inv, ay * inv);
}

// ---------- launch ----------
extern "C" void kernel_launch(void* const* d_in, const int* in_sizes, int n_in,
                              void* d_out, int out_size, void* d_ws, size_t ws_size,
                              hipStream_t stream) {
    const float* x     = (const float*)d_in[0];
    const float* alpha = (const float*)d_in[1];
    const int*   ei    = (const int*)d_in[2];
    const float* W1 = (const float*)d_in[4];
    const float* b1 = (const float*)d_in[5];
    const float* W2 = (const float*)d_in[6];
    const float* b2 = (const float*)d_in[7];
    const float* W3 = (const float*)d_in[8];
    const float* b3 = (const float*)d_in[9];
    float* out = (float*)d_out;

    const int N = in_sizes[0] / 256;   // 100000
    const int E = in_sizes[1];         // 640000
    const int IN = 256, H1 = 512, H2 = 256, D = 128;

    char* ws = (char*)d_ws;
    size_t off = 0;
    auto take = [&](size_t bytes) { char* p = ws + off; off = (off + bytes + 255) & ~(size_t)255; return p; };
    unsigned short* xbf  = (unsigned short*)take((size_t)N * IN * 2);   // reused as h2bf
    unsigned short* h1bf = (unsigned short*)take((size_t)N * H1 * 2);   // reused for CSR after GEMM2
    unsigned short* hbf  = (unsigned short*)take((size_t)N * D  * 2);
    unsigned short* w1bf = (unsigned short*)take((size_t)H1 * IN * 2);
    unsigned short* w2bf = (unsigned short*)take((size_t)H2 * H1 * 2);
    unsigned short* w3bf = (unsigned short*)take((size_t)D  * H2 * 2);
    unsigned short* h2bf = xbf;

    // CSR scratch carved from h1bf region (dead after GEMM2; ~6.8 MB << 102 MB)
    {
        size_t coff = 0;
        char* cbase = (char*)h1bf;
        auto ctake = [&](size_t bytes) { char* p = cbase + coff; coff = (coff + bytes + 255) & ~(size_t)255; return p; };
        (void)ctake;
    }
    char* cbase = (char*)h1bf;
    size_t coff = 0;
    auto ctake = [&](size_t bytes) { char* p = cbase + coff; coff = (coff + bytes + 255) & ~(size_t)255; return p; };
    unsigned long long* deg = (unsigned long long*)ctake((size_t)N * 8);
    int*  rowptr   = (int*)ctake((size_t)N * 4);
    int*  cursor   = (int*)ctake((size_t)N * 4);
    int*  partials = (int*)ctake(256 * 4);
    int2* recs     = (int2*)ctake((size_t)E * 8);

    // ---- MLP ----
    cast_f32_bf16<<<(N * IN / 4 + 255) / 256, 256, 0, stream>>>(x,  xbf,  N * IN);
    cast_f32_bf16<<<(H1 * IN / 4 + 255) / 256, 256, 0, stream>>>(W1, w1bf, H1 * IN);
    cast_f32_bf16<<<(H2 * H1 / 4 + 255) / 256, 256, 0, stream>>>(W2, w2bf, H2 * H1);
    cast_f32_bf16<<<(D * H2 / 4 + 255) / 256, 256, 0, stream>>>(W3, w3bf, D * H2);

    const int mblk = (N + TM - 1) / TM;
    dim3 blk(256);
    gemm_bt<true ><<<dim3(mblk, H1 / TN), blk, 0, stream>>>(xbf,  w1bf, b1, h1bf, N, H1, IN);
    gemm_bt<true ><<<dim3(mblk, H2 / TN), blk, 0, stream>>>(h1bf, w2bf, b2, h2bf, N, H2, H1);
    gemm_bt<false><<<dim3(mblk, D / TN),  blk, 0, stream>>>(h2bf, w3bf, b3, hbf,  N, D,  H2);

    // ---- CSR build (h1bf region now dead) ----
    hipMemsetAsync(deg, 0, (size_t)N * 8, stream);
    edge_hist<<<(E + 255) / 256, blk, 0, stream>>>(ei, alpha, deg, E);
    const int nb1 = (N + 1023) / 1024;   // 98
    scan1<<<nb1, blk, 0, stream>>>(deg, rowptr, partials, N);
    scan2<<<1, blk, 0, stream>>>(partials, nb1);
    scan3<<<(N + 255) / 256, blk, 0, stream>>>(rowptr, cursor, partials, N);
    edge_fill<<<(E + 255) / 256, blk, 0, stream>>>(ei, alpha, cursor, recs, E);

    // ---- gather + mean ----
    node_gather<<<(N + 3) / 4, blk, 0, stream>>>(hbf, deg, rowptr, recs, out, N);
}

// Round 3
// 479.925 us; speedup vs baseline: 1.4654x; 1.0901x over previous
//
#include <hip/hip_runtime.h>

// ---------- helpers ----------
typedef __attribute__((ext_vector_type(8))) short short8;
typedef __attribute__((ext_vector_type(4))) float f32x4;

__device__ __forceinline__ unsigned short f2bf(float f) {
    union { float f; unsigned u; } v; v.f = f;
    unsigned r = v.u + 0x7FFFu + ((v.u >> 16) & 1u);   // RNE
    return (unsigned short)(r >> 16);
}
__device__ __forceinline__ float bf2f(unsigned short h) {
    union { unsigned u; float f; } v; v.u = ((unsigned)h) << 16;
    return v.f;
}

#define GLD16(gptr, lptr)                                                     \
    __builtin_amdgcn_global_load_lds(                                         \
        (const __attribute__((address_space(1))) unsigned int*)(gptr),        \
        (__attribute__((address_space(3))) unsigned int*)(lptr), 16, 0, 0)

// ---------- cast f32 -> bf16 (4 elems / thread) ----------
__global__ __launch_bounds__(256) void cast_f32_bf16(
    const float* __restrict__ src, unsigned short* __restrict__ dst, int n)
{
    int t = (blockIdx.x * 256 + threadIdx.x) * 4;
    if (t >= n) return;
    float4 v = *(const float4*)(src + t);
    unsigned long long p =
        (unsigned long long)f2bf(v.x)
      | ((unsigned long long)f2bf(v.y) << 16)
      | ((unsigned long long)f2bf(v.z) << 32)
      | ((unsigned long long)f2bf(v.w) << 48);
    *(unsigned long long*)(dst + t) = p;
}

// ---------- MFMA GEMM: C[M,N] = act(A[M,K] * B[N,K]^T + bias) ----------
// m97-style: global_load_lds(16B) staging, unpadded LDS, XOR chunk swizzle.
#define TM 128
#define TN 128
#define BK 64

template<bool TANH>
__global__ __launch_bounds__(256) void gemm_bt(
    const unsigned short* __restrict__ A, const unsigned short* __restrict__ B,
    const float* __restrict__ bias, unsigned short* __restrict__ C,
    int M, int N, int K)
{
    __shared__ __align__(16) short As[TM][BK];
    __shared__ __align__(16) short Bs[TN][BK];

    const int tid  = threadIdx.x;
    const int wave = tid >> 6;
    const int lane = tid & 63;
    const int m0 = blockIdx.x * TM;
    const int n0 = blockIdx.y * TN;
    const int wm = (wave >> 1) * 64;
    const int wn = (wave & 1) * 64;
    const int lm = lane & 15;
    const int quad = lane >> 4;

    // staging geometry: lane l lands at LDS row (base + l/8), chunk (l&7).
    // XOR swizzle: position p holds global chunk p ^ (row&7); with base%8==0
    // the per-lane source chunk is ((l&7) ^ (l>>3)) -- lane-constant.
    const int srow = lane >> 3;                  // 0..7
    const int scol = ((lane & 7) ^ srow) * 8;    // swizzled source chunk (shorts)

    // fragment-read swizzled chunk positions (lane-constant, rows have row&7==lm&7)
    const int cc0 = (quad ^ (lm & 7)) * 8;        // ks = 0
    const int cc1 = ((4 + quad) ^ (lm & 7)) * 8;  // ks = 32

    f32x4 acc[4][4] = {};

    for (int k0 = 0; k0 < K; k0 += BK) {
        #pragma unroll
        for (int i = 0; i < 4; ++i) {
            int row = wave * 32 + i * 8;         // wave-uniform LDS base row
            int gr = m0 + row + srow; if (gr >= M) gr = M - 1;
            GLD16(A + (size_t)gr * K + k0 + scol, &As[row][0]);
            GLD16(B + (size_t)(n0 + row + srow) * K + k0 + scol, &Bs[row][0]);
        }
        __syncthreads();

        #pragma unroll
        for (int ks = 0; ks < BK; ks += 32) {
            const int cc = (ks == 0) ? cc0 : cc1;
            short8 af[4], bf_[4];
            #pragma unroll
            for (int i = 0; i < 4; ++i) {
                af[i]  = *(const short8*)&As[wm + i * 16 + lm][cc];
                bf_[i] = *(const short8*)&Bs[wn + i * 16 + lm][cc];
            }
            #pragma unroll
            for (int im = 0; im < 4; ++im)
                #pragma unroll
                for (int in = 0; in < 4; ++in)
                    acc[im][in] = __builtin_amdgcn_mfma_f32_16x16x32_bf16(
                        af[im], bf_[in], acc[im][in], 0, 0, 0);
        }
        __syncthreads();
    }

    #pragma unroll
    for (int im = 0; im < 4; ++im) {
        int gm_base = m0 + wm + im * 16 + quad * 4;
        #pragma unroll
        for (int in = 0; in < 4; ++in) {
            int gn = n0 + wn + in * 16 + lm;
            float bv = bias[gn];
            #pragma unroll
            for (int r = 0; r < 4; ++r) {
                int gm = gm_base + r;
                if (gm < M) {
                    float v = acc[im][in][r] + bv;
                    if (TANH) v = tanhf(v);
                    C[(size_t)gm * N + gn] = f2bf(v);
                }
            }
        }
    }
}

// ---------- edge histogram: packed (degAll<<32 | degGated) ----------
__global__ __launch_bounds__(256) void edge_hist(
    const int* __restrict__ ei, const float* __restrict__ alpha,
    unsigned long long* __restrict__ deg, int E)
{
    int e = blockIdx.x * 256 + threadIdx.x;
    if (e >= E) return;
    int dst = ei[E + e];
    float gate = 2.0f * fmaxf(alpha[e] - 0.5f, 0.0f);
    atomicAdd(&deg[dst], 0x100000000ULL | (gate > 0.0f ? 1ULL : 0ULL));
}

// ---------- scan step 1: per-block (1024 elems) exclusive scan ----------
__global__ __launch_bounds__(256) void scan1(
    const unsigned long long* __restrict__ deg, int* __restrict__ rowptr,
    int* __restrict__ partials, int N)
{
    __shared__ int sums[256];
    int base = blockIdx.x * 1024 + threadIdx.x * 4;
    int v[4];
    #pragma unroll
    for (int i = 0; i < 4; ++i) {
        int idx = base + i;
        v[i] = (idx < N) ? (int)(deg[idx] & 0xffffffffULL) : 0;
    }
    int s = v[0] + v[1] + v[2] + v[3];
    sums[threadIdx.x] = s;
    __syncthreads();
    for (int off = 1; off < 256; off <<= 1) {
        int t = (threadIdx.x >= off) ? sums[threadIdx.x - off] : 0;
        __syncthreads();
        sums[threadIdx.x] += t;
        __syncthreads();
    }
    int excl = sums[threadIdx.x] - s;
    if (threadIdx.x == 255) partials[blockIdx.x] = sums[255];
    int run = excl;
    #pragma unroll
    for (int i = 0; i < 4; ++i) {
        int idx = base + i;
        if (idx < N) rowptr[idx] = run;
        run += v[i];
    }
}

// ---------- scan step 2: scan the block partials (single block) ----------
__global__ __launch_bounds__(256) void scan2(int* __restrict__ partials, int nb)
{
    __shared__ int s[256];
    int v = (threadIdx.x < nb) ? partials[threadIdx.x] : 0;
    s[threadIdx.x] = v;
    __syncthreads();
    for (int off = 1; off < 256; off <<= 1) {
        int t = (threadIdx.x >= off) ? s[threadIdx.x - off] : 0;
        __syncthreads();
        s[threadIdx.x] += t;
        __syncthreads();
    }
    partials[threadIdx.x] = s[threadIdx.x] - v;   // exclusive
}

// ---------- scan step 3: add block offsets; init cursor ----------
__global__ __launch_bounds__(256) void scan3(
    int* __restrict__ rowptr, int* __restrict__ cursor,
    const int* __restrict__ partials, int N)
{
    int i = blockIdx.x * 256 + threadIdx.x;
    if (i >= N) return;
    int r = rowptr[i] + partials[i >> 10];
    rowptr[i] = r;
    cursor[i] = r;
}

// ---------- fill CSR with gated edges only ----------
__global__ __launch_bounds__(256) void edge_fill(
    const int* __restrict__ ei, const float* __restrict__ alpha,
    int* __restrict__ cursor, int2* __restrict__ recs, int E)
{
    int e = blockIdx.x * 256 + threadIdx.x;
    if (e >= E) return;
    float gate = 2.0f * fmaxf(alpha[e] - 0.5f, 0.0f);
    if (gate > 0.0f) {
        int dst = ei[E + e];
        int src = ei[e];
        int pos = atomicAdd(&cursor[dst], 1);
        recs[pos] = make_int2(src, __float_as_int(gate));
    }
}

// ---------- per-node gather + mean: one wave per node ----------
__global__ __launch_bounds__(256) void node_gather(
    const unsigned short* __restrict__ h, const unsigned long long* __restrict__ deg,
    const int* __restrict__ rowptr, const int2* __restrict__ recs,
    float* __restrict__ out, int N)
{
    int wave = threadIdx.x >> 6;
    int lane = threadIdx.x & 63;
    int node = blockIdx.x * 4 + wave;
    if (node >= N) return;
    unsigned long long d = deg[node];
    int dAll  = __builtin_amdgcn_readfirstlane((int)(d >> 32));
    int dG    = __builtin_amdgcn_readfirstlane((int)(d & 0xffffffffULL));
    int start = __builtin_amdgcn_readfirstlane(rowptr[node]);
    float ax = 0.0f, ay = 0.0f;
    for (int j = 0; j < dG; ++j) {
        int2 rec = recs[start + j];                 // wave-uniform load
        float gate = __int_as_float(rec.y);
        unsigned u = *(const unsigned*)(h + ((size_t)rec.x << 7) + lane * 2);
        ax += bf2f((unsigned short)(u & 0xffffu)) * gate;
        ay += bf2f((unsigned short)(u >> 16)) * gate;
    }
    float inv = 1.0f / fmaxf((float)dAll, 1.0f);
    *(float2*)(out + ((size_t)node << 7) + lane * 2) = make_float2(ax * inv, ay * inv);
}

// ---------- launch ----------
extern "C" void kernel_launch(void* const* d_in, const int* in_sizes, int n_in,
                              void* d_out, int out_size, void* d_ws, size_t ws_size,
                              hipStream_t stream) {
    const float* x     = (const float*)d_in[0];
    const float* alpha = (const float*)d_in[1];
    const int*   ei    = (const int*)d_in[2];
    const float* W1 = (const float*)d_in[4];
    const float* b1 = (const float*)d_in[5];
    const float* W2 = (const float*)d_in[6];
    const float* b2 = (const float*)d_in[7];
    const float* W3 = (const float*)d_in[8];
    const float* b3 = (const float*)d_in[9];
    float* out = (float*)d_out;

    const int N = in_sizes[0] / 256;   // 100000
    const int E = in_sizes[1];         // 640000
    const int IN = 256, H1 = 512, H2 = 256, D = 128;

    char* ws = (char*)d_ws;
    size_t off = 0;
    auto take = [&](size_t bytes) { char* p = ws + off; off = (off + bytes + 255) & ~(size_t)255; return p; };
    unsigned short* xbf  = (unsigned short*)take((size_t)N * IN * 2);   // reused as h2bf
    unsigned short* h1bf = (unsigned short*)take((size_t)N * H1 * 2);   // reused for CSR after GEMM2
    unsigned short* hbf  = (unsigned short*)take((size_t)N * D  * 2);
    unsigned short* w1bf = (unsigned short*)take((size_t)H1 * IN * 2);
    unsigned short* w2bf = (unsigned short*)take((size_t)H2 * H1 * 2);
    unsigned short* w3bf = (unsigned short*)take((size_t)D  * H2 * 2);
    unsigned short* h2bf = xbf;

    // CSR scratch carved from h1bf region (dead after GEMM2; ~6.8 MB << 102 MB)
    char* cbase = (char*)h1bf;
    size_t coff = 0;
    auto ctake = [&](size_t bytes) { char* p = cbase + coff; coff = (coff + bytes + 255) & ~(size_t)255; return p; };
    unsigned long long* deg = (unsigned long long*)ctake((size_t)N * 8);
    int*  rowptr   = (int*)ctake((size_t)N * 4);
    int*  cursor   = (int*)ctake((size_t)N * 4);
    int*  partials = (int*)ctake(256 * 4);
    int2* recs     = (int2*)ctake((size_t)E * 8);

    // ---- MLP ----
    cast_f32_bf16<<<(N * IN / 4 + 255) / 256, 256, 0, stream>>>(x,  xbf,  N * IN);
    cast_f32_bf16<<<(H1 * IN / 4 + 255) / 256, 256, 0, stream>>>(W1, w1bf, H1 * IN);
    cast_f32_bf16<<<(H2 * H1 / 4 + 255) / 256, 256, 0, stream>>>(W2, w2bf, H2 * H1);
    cast_f32_bf16<<<(D * H2 / 4 + 255) / 256, 256, 0, stream>>>(W3, w3bf, D * H2);

    const int mblk = (N + TM - 1) / TM;
    dim3 blk(256);
    gemm_bt<true ><<<dim3(mblk, H1 / TN), blk, 0, stream>>>(xbf,  w1bf, b1, h1bf, N, H1, IN);
    gemm_bt<true ><<<dim3(mblk, H2 / TN), blk, 0, stream>>>(h1bf, w2bf, b2, h2bf, N, H2, H1);
    gemm_bt<false><<<dim3(mblk, D / TN),  blk, 0, stream>>>(h2bf, w3bf, b3, hbf,  N, D,  H2);

    // ---- CSR build (h1bf region now dead) ----
    hipMemsetAsync(deg, 0, (size_t)N * 8, stream);
    edge_hist<<<(E + 255) / 256, blk, 0, stream>>>(ei, alpha, deg, E);
    const int nb1 = (N + 1023) / 1024;   // 98
    scan1<<<nb1, blk, 0, stream>>>(deg, rowptr, partials, N);
    scan2<<<1, blk, 0, stream>>>(partials, nb1);
    scan3<<<(N + 255) / 256, blk, 0, stream>>>(rowptr, cursor, partials, N);
    edge_fill<<<(E + 255) / 256, blk, 0, stream>>>(ei, alpha, cursor, recs, E);

    // ---- gather + mean ----
    node_gather<<<(N + 3) / 4, blk, 0, stream>>>(hbf, deg, rowptr, recs, out, N);
}

// Round 4
// 436.769 us; speedup vs baseline: 1.6102x; 1.0988x over previous
//
#include <hip/hip_runtime.h>

// ---------- helpers ----------
typedef __attribute__((ext_vector_type(8))) short short8;
typedef __attribute__((ext_vector_type(4))) float f32x4;

__device__ __forceinline__ unsigned short f2bf(float f) {
    union { float f; unsigned u; } v; v.f = f;
    unsigned r = v.u + 0x7FFFu + ((v.u >> 16) & 1u);   // RNE
    return (unsigned short)(r >> 16);
}
__device__ __forceinline__ float bf2f(unsigned short h) {
    union { unsigned u; float f; } v; v.u = ((unsigned)h) << 16;
    return v.f;
}

// fast tanh: 1 v_exp_f32 + 1 v_rcp_f32, ~8 VALU inst. rel err ~1e-5 << bf16 ulp.
__device__ __forceinline__ float tanh_fast(float x) {
    float xc = fminf(fmaxf(x, -9.0f), 9.0f);
    float t  = __expf(2.0f * xc);
    return (t - 1.0f) * __builtin_amdgcn_rcpf(t + 1.0f);
}

#define GLD16(gptr, lptr)                                                     \
    __builtin_amdgcn_global_load_lds(                                         \
        (const __attribute__((address_space(1))) unsigned int*)(gptr),        \
        (__attribute__((address_space(3))) unsigned int*)(lptr), 16, 0, 0)

// ---------- cast f32 -> bf16 (4 elems / thread) ----------
__global__ __launch_bounds__(256) void cast_f32_bf16(
    const float* __restrict__ src, unsigned short* __restrict__ dst, int n)
{
    int t = (blockIdx.x * 256 + threadIdx.x) * 4;
    if (t >= n) return;
    float4 v = *(const float4*)(src + t);
    unsigned long long p =
        (unsigned long long)f2bf(v.x)
      | ((unsigned long long)f2bf(v.y) << 16)
      | ((unsigned long long)f2bf(v.z) << 32)
      | ((unsigned long long)f2bf(v.w) << 48);
    *(unsigned long long*)(dst + t) = p;
}

// ---------- MFMA GEMM: C[M,N] = act(A[M,K] * B[N,K]^T + bias) ----------
// m97-style: global_load_lds(16B) staging, unpadded LDS, XOR chunk swizzle.
#define TM 128
#define TN 128
#define BK 64

template<bool TANH>
__global__ __launch_bounds__(256) void gemm_bt(
    const unsigned short* __restrict__ A, const unsigned short* __restrict__ B,
    const float* __restrict__ bias, unsigned short* __restrict__ C,
    int M, int N, int K)
{
    __shared__ __align__(16) short As[TM][BK];
    __shared__ __align__(16) short Bs[TN][BK];

    const int tid  = threadIdx.x;
    const int wave = tid >> 6;
    const int lane = tid & 63;
    const int m0 = blockIdx.x * TM;
    const int n0 = blockIdx.y * TN;
    const int wm = (wave >> 1) * 64;
    const int wn = (wave & 1) * 64;
    const int lm = lane & 15;
    const int quad = lane >> 4;

    const int srow = lane >> 3;                  // 0..7
    const int scol = ((lane & 7) ^ srow) * 8;    // swizzled source chunk (shorts)

    const int cc0 = (quad ^ (lm & 7)) * 8;        // ks = 0
    const int cc1 = ((4 + quad) ^ (lm & 7)) * 8;  // ks = 32

    f32x4 acc[4][4] = {};

    for (int k0 = 0; k0 < K; k0 += BK) {
        #pragma unroll
        for (int i = 0; i < 4; ++i) {
            int row = wave * 32 + i * 8;         // wave-uniform LDS base row
            int gr = m0 + row + srow; if (gr >= M) gr = M - 1;
            GLD16(A + (size_t)gr * K + k0 + scol, &As[row][0]);
            GLD16(B + (size_t)(n0 + row + srow) * K + k0 + scol, &Bs[row][0]);
        }
        __syncthreads();

        #pragma unroll
        for (int ks = 0; ks < BK; ks += 32) {
            const int cc = (ks == 0) ? cc0 : cc1;
            short8 af[4], bf_[4];
            #pragma unroll
            for (int i = 0; i < 4; ++i) {
                af[i]  = *(const short8*)&As[wm + i * 16 + lm][cc];
                bf_[i] = *(const short8*)&Bs[wn + i * 16 + lm][cc];
            }
            #pragma unroll
            for (int im = 0; im < 4; ++im)
                #pragma unroll
                for (int in = 0; in < 4; ++in)
                    acc[im][in] = __builtin_amdgcn_mfma_f32_16x16x32_bf16(
                        af[im], bf_[in], acc[im][in], 0, 0, 0);
        }
        __syncthreads();
    }

    #pragma unroll
    for (int im = 0; im < 4; ++im) {
        int gm_base = m0 + wm + im * 16 + quad * 4;
        #pragma unroll
        for (int in = 0; in < 4; ++in) {
            int gn = n0 + wn + in * 16 + lm;
            float bv = bias[gn];
            #pragma unroll
            for (int r = 0; r < 4; ++r) {
                int gm = gm_base + r;
                if (gm < M) {
                    float v = acc[im][in][r] + bv;
                    if (TANH) v = tanh_fast(v);
                    C[(size_t)gm * N + gn] = f2bf(v);
                }
            }
        }
    }
}

// ---------- edge histogram: packed (degAll<<32 | degGated) ----------
__global__ __launch_bounds__(256) void edge_hist(
    const int* __restrict__ ei, const float* __restrict__ alpha,
    unsigned long long* __restrict__ deg, int E)
{
    int e = blockIdx.x * 256 + threadIdx.x;
    if (e >= E) return;
    int dst = ei[E + e];
    float gate = 2.0f * fmaxf(alpha[e] - 0.5f, 0.0f);
    atomicAdd(&deg[dst], 0x100000000ULL | (gate > 0.0f ? 1ULL : 0ULL));
}

// ---------- scan step 1: per-block (1024 elems) exclusive scan ----------
__global__ __launch_bounds__(256) void scan1(
    const unsigned long long* __restrict__ deg, int* __restrict__ rowptr,
    int* __restrict__ partials, int N)
{
    __shared__ int sums[256];
    int base = blockIdx.x * 1024 + threadIdx.x * 4;
    int v[4];
    #pragma unroll
    for (int i = 0; i < 4; ++i) {
        int idx = base + i;
        v[i] = (idx < N) ? (int)(deg[idx] & 0xffffffffULL) : 0;
    }
    int s = v[0] + v[1] + v[2] + v[3];
    sums[threadIdx.x] = s;
    __syncthreads();
    for (int off = 1; off < 256; off <<= 1) {
        int t = (threadIdx.x >= off) ? sums[threadIdx.x - off] : 0;
        __syncthreads();
        sums[threadIdx.x] += t;
        __syncthreads();
    }
    int excl = sums[threadIdx.x] - s;
    if (threadIdx.x == 255) partials[blockIdx.x] = sums[255];
    int run = excl;
    #pragma unroll
    for (int i = 0; i < 4; ++i) {
        int idx = base + i;
        if (idx < N) rowptr[idx] = run;
        run += v[i];
    }
}

// ---------- scan step 2: scan the block partials (single block) ----------
__global__ __launch_bounds__(256) void scan2(int* __restrict__ partials, int nb)
{
    __shared__ int s[256];
    int v = (threadIdx.x < nb) ? partials[threadIdx.x] : 0;
    s[threadIdx.x] = v;
    __syncthreads();
    for (int off = 1; off < 256; off <<= 1) {
        int t = (threadIdx.x >= off) ? s[threadIdx.x - off] : 0;
        __syncthreads();
        s[threadIdx.x] += t;
        __syncthreads();
    }
    partials[threadIdx.x] = s[threadIdx.x] - v;   // exclusive
}

// ---------- scan step 3: add block offsets; init cursor ----------
__global__ __launch_bounds__(256) void scan3(
    int* __restrict__ rowptr, int* __restrict__ cursor,
    const int* __restrict__ partials, int N)
{
    int i = blockIdx.x * 256 + threadIdx.x;
    if (i >= N) return;
    int r = rowptr[i] + partials[i >> 10];
    rowptr[i] = r;
    cursor[i] = r;
}

// ---------- fill CSR with gated edges only ----------
__global__ __launch_bounds__(256) void edge_fill(
    const int* __restrict__ ei, const float* __restrict__ alpha,
    int* __restrict__ cursor, int2* __restrict__ recs, int E)
{
    int e = blockIdx.x * 256 + threadIdx.x;
    if (e >= E) return;
    float gate = 2.0f * fmaxf(alpha[e] - 0.5f, 0.0f);
    if (gate > 0.0f) {
        int dst = ei[E + e];
        int src = ei[e];
        int pos = atomicAdd(&cursor[dst], 1);
        recs[pos] = make_int2(src, __float_as_int(gate));
    }
}

// ---------- per-node gather + mean: one wave per node ----------
__global__ __launch_bounds__(256) void node_gather(
    const unsigned short* __restrict__ h, const unsigned long long* __restrict__ deg,
    const int* __restrict__ rowptr, const int2* __restrict__ recs,
    float* __restrict__ out, int N)
{
    int wave = threadIdx.x >> 6;
    int lane = threadIdx.x & 63;
    int node = blockIdx.x * 4 + wave;
    if (node >= N) return;
    unsigned long long d = deg[node];
    int dAll  = __builtin_amdgcn_readfirstlane((int)(d >> 32));
    int dG    = __builtin_amdgcn_readfirstlane((int)(d & 0xffffffffULL));
    int start = __builtin_amdgcn_readfirstlane(rowptr[node]);
    float ax = 0.0f, ay = 0.0f;
    for (int j = 0; j < dG; ++j) {
        int2 rec = recs[start + j];                 // wave-uniform load
        float gate = __int_as_float(rec.y);
        unsigned u = *(const unsigned*)(h + ((size_t)rec.x << 7) + lane * 2);
        ax += bf2f((unsigned short)(u & 0xffffu)) * gate;
        ay += bf2f((unsigned short)(u >> 16)) * gate;
    }
    float inv = 1.0f / fmaxf((float)dAll, 1.0f);
    *(float2*)(out + ((size_t)node << 7) + lane * 2) = make_float2(ax * inv, ay * inv);
}

// ---------- launch ----------
extern "C" void kernel_launch(void* const* d_in, const int* in_sizes, int n_in,
                              void* d_out, int out_size, void* d_ws, size_t ws_size,
                              hipStream_t stream) {
    const float* x     = (const float*)d_in[0];
    const float* alpha = (const float*)d_in[1];
    const int*   ei    = (const int*)d_in[2];
    const float* W1 = (const float*)d_in[4];
    const float* b1 = (const float*)d_in[5];
    const float* W2 = (const float*)d_in[6];
    const float* b2 = (const float*)d_in[7];
    const float* W3 = (const float*)d_in[8];
    const float* b3 = (const float*)d_in[9];
    float* out = (float*)d_out;

    const int N = in_sizes[0] / 256;   // 100000
    const int E = in_sizes[1];         // 640000
    const int IN = 256, H1 = 512, H2 = 256, D = 128;

    char* ws = (char*)d_ws;
    size_t off = 0;
    auto take = [&](size_t bytes) { char* p = ws + off; off = (off + bytes + 255) & ~(size_t)255; return p; };
    unsigned short* xbf  = (unsigned short*)take((size_t)N * IN * 2);   // reused as h2bf
    unsigned short* h1bf = (unsigned short*)take((size_t)N * H1 * 2);   // reused for CSR after GEMM2
    unsigned short* hbf  = (unsigned short*)take((size_t)N * D  * 2);
    unsigned short* w1bf = (unsigned short*)take((size_t)H1 * IN * 2);
    unsigned short* w2bf = (unsigned short*)take((size_t)H2 * H1 * 2);
    unsigned short* w3bf = (unsigned short*)take((size_t)D  * H2 * 2);
    unsigned short* h2bf = xbf;

    // CSR scratch carved from h1bf region (dead after GEMM2; ~6.8 MB << 102 MB)
    char* cbase = (char*)h1bf;
    size_t coff = 0;
    auto ctake = [&](size_t bytes) { char* p = cbase + coff; coff = (coff + bytes + 255) & ~(size_t)255; return p; };
    unsigned long long* deg = (unsigned long long*)ctake((size_t)N * 8);
    int*  rowptr   = (int*)ctake((size_t)N * 4);
    int*  cursor   = (int*)ctake((size_t)N * 4);
    int*  partials = (int*)ctake(256 * 4);
    int2* recs     = (int2*)ctake((size_t)E * 8);

    // ---- MLP ----
    cast_f32_bf16<<<(N * IN / 4 + 255) / 256, 256, 0, stream>>>(x,  xbf,  N * IN);
    cast_f32_bf16<<<(H1 * IN / 4 + 255) / 256, 256, 0, stream>>>(W1, w1bf, H1 * IN);
    cast_f32_bf16<<<(H2 * H1 / 4 + 255) / 256, 256, 0, stream>>>(W2, w2bf, H2 * H1);
    cast_f32_bf16<<<(D * H2 / 4 + 255) / 256, 256, 0, stream>>>(W3, w3bf, D * H2);

    const int mblk = (N + TM - 1) / TM;
    dim3 blk(256);
    gemm_bt<true ><<<dim3(mblk, H1 / TN), blk, 0, stream>>>(xbf,  w1bf, b1, h1bf, N, H1, IN);
    gemm_bt<true ><<<dim3(mblk, H2 / TN), blk, 0, stream>>>(h1bf, w2bf, b2, h2bf, N, H2, H1);
    gemm_bt<false><<<dim3(mblk, D / TN),  blk, 0, stream>>>(h2bf, w3bf, b3, hbf,  N, D,  H2);

    // ---- CSR build (h1bf region now dead) ----
    hipMemsetAsync(deg, 0, (size_t)N * 8, stream);
    edge_hist<<<(E + 255) / 256, blk, 0, stream>>>(ei, alpha, deg, E);
    const int nb1 = (N + 1023) / 1024;   // 98
    scan1<<<nb1, blk, 0, stream>>>(deg, rowptr, partials, N);
    scan2<<<1, blk, 0, stream>>>(partials, nb1);
    scan3<<<(N + 255) / 256, blk, 0, stream>>>(rowptr, cursor, partials, N);
    edge_fill<<<(E + 255) / 256, blk, 0, stream>>>(ei, alpha, cursor, recs, E);

    // ---- gather + mean ----
    node_gather<<<(N + 3) / 4, blk, 0, stream>>>(hbf, deg, rowptr, recs, out, N);
}